// Round 6
// baseline (257.926 us; speedup 1.0000x reference)
//
#include <hip/hip_runtime.h>
#include <stdint.h>

typedef __bf16 bf16_t;
typedef bf16_t bf16x8 __attribute__((ext_vector_type(8)));
typedef float f32x4 __attribute__((ext_vector_type(4)));
typedef unsigned short us8 __attribute__((ext_vector_type(8)));
typedef unsigned short us4 __attribute__((ext_vector_type(4)));
typedef unsigned int u32x4 __attribute__((ext_vector_type(4)));

#define B_ 4
#define T_ 4096
#define C_ 1024
#define D_ 128

#define NCHUNK_PB 144   // per batch: sum over 32 q-tiles(128 rows) of ceil((jt2+1)/4)
#define QSCALE 0.12751744f  // (1/sqrt(128)) * log2(e), folded into Q

__device__ __forceinline__ uint16_t f2bf(float f) {
    union { float f; uint32_t u; } v; v.f = f;
    uint32_t u = v.u;
    uint32_t r = (u + 0x7fffu + ((u >> 16) & 1u)) >> 16;
    return (uint16_t)r;
}

// round-half-up bf16 (2 VALU)
__device__ __forceinline__ uint16_t bfru(float f) {
    return (uint16_t)((__float_as_uint(f) + 0x8000u) >> 16);
}

__device__ __forceinline__ float bf2f(uint16_t u) {
    return __uint_as_float((uint32_t)u << 16);
}

// ---------------------------------------------------------------------------
// Kernel 1: W[C,D] fp32 -> WT[w][n][k] bf16 (transposed), w in {q,k,v}
// ---------------------------------------------------------------------------
__global__ __launch_bounds__(256) void prep_w(const float* __restrict__ Wq,
                                              const float* __restrict__ Wk,
                                              const float* __restrict__ Wv,
                                              uint16_t* __restrict__ WT) {
    int idx = blockIdx.x * 256 + threadIdx.x;
    if (idx >= 3 * D_ * C_) return;
    int w   = idx / (D_ * C_);
    int rem = idx - w * (D_ * C_);
    int n   = rem / C_;
    int k   = rem - n * C_;
    const float* W = (w == 0) ? Wq : (w == 1) ? Wk : Wv;
    WT[idx] = f2bf(W[(size_t)k * D_ + n]);
}

// ---------------------------------------------------------------------------
// Kernel 2: QKV projection (R4 structure, no prefetch). grid = 3 W x 256
// M-tiles(64 rows) = 768 blocks. BK=64. Q gets QSCALE folded in.
// ---------------------------------------------------------------------------
#define GST 72   // 64+8 elems leading-dim pad

__global__ __launch_bounds__(256) void qkv_gemm(const float* __restrict__ x,
                                                const uint16_t* __restrict__ WT,
                                                uint16_t* __restrict__ qb,
                                                uint16_t* __restrict__ kb,
                                                uint16_t* __restrict__ vT) {
    __shared__ __align__(16) uint16_t A_lds[64 * GST];
    __shared__ __align__(16) uint16_t W_lds[128 * GST];

    int tid  = threadIdx.x;
    int lane = tid & 63;
    int wave = tid >> 6;
    int quad = lane >> 4;
    int lx   = lane & 15;
    int wm   = wave >> 1, wn = wave & 1;

    int bx   = blockIdx.x;
    int wsel = bx % 3;
    int m0   = (bx / 3) * 64;
    const uint16_t* Wp = WT + (size_t)wsel * (D_ * C_);

    f32x4 acc[2][4];
    for (int mf = 0; mf < 2; mf++)
        for (int nf = 0; nf < 4; nf++)
            acc[mf][nf] = (f32x4){0.f, 0.f, 0.f, 0.f};

    int arow = tid >> 2, acb = (tid & 3) * 16;  // A: 16 floats/thread
    int wrow = tid >> 1, wcb = (tid & 1) * 32;  // W: 32 bf16/thread

    for (int k0 = 0; k0 < C_; k0 += 64) {
        // stage A (fp32 -> bf16 packed via v_perm)
        {
            const float* xp = x + (size_t)(m0 + arow) * C_ + k0 + acb;
            uint32_t d[8];
#pragma unroll
            for (int j = 0; j < 4; j++) {
                float4 f = *(const float4*)(xp + j * 4);
                uint32_t u0 = __float_as_uint(f.x) + 0x8000u;
                uint32_t u1 = __float_as_uint(f.y) + 0x8000u;
                uint32_t u2 = __float_as_uint(f.z) + 0x8000u;
                uint32_t u3 = __float_as_uint(f.w) + 0x8000u;
                d[2 * j]     = __builtin_amdgcn_perm(u1, u0, 0x07060302);
                d[2 * j + 1] = __builtin_amdgcn_perm(u3, u2, 0x07060302);
            }
            *(u32x4*)&A_lds[arow * GST + acb]     = (u32x4){d[0], d[1], d[2], d[3]};
            *(u32x4*)&A_lds[arow * GST + acb + 8] = (u32x4){d[4], d[5], d[6], d[7]};
        }
        // stage W slice (bf16, transposed already)
        {
            const uint16_t* wp = Wp + (size_t)wrow * C_ + k0 + wcb;
#pragma unroll
            for (int i = 0; i < 4; i++)
                *(us8*)&W_lds[wrow * GST + wcb + i * 8] = *(const us8*)(wp + i * 8);
        }
        __syncthreads();

#pragma unroll
        for (int kc = 0; kc < 2; kc++) {
            bf16x8 af[2];
#pragma unroll
            for (int mf = 0; mf < 2; mf++)
                af[mf] = *(const bf16x8*)&A_lds[(wm * 32 + mf * 16 + lx) * GST + kc * 32 + quad * 8];
#pragma unroll
            for (int nf = 0; nf < 4; nf++) {
                bf16x8 bf = *(const bf16x8*)&W_lds[(wn * 64 + nf * 16 + lx) * GST + kc * 32 + quad * 8];
                acc[0][nf] = __builtin_amdgcn_mfma_f32_16x16x32_bf16(af[0], bf, acc[0][nf], 0, 0, 0);
                acc[1][nf] = __builtin_amdgcn_mfma_f32_16x16x32_bf16(af[1], bf, acc[1][nf], 0, 0, 0);
            }
        }
        __syncthreads();
    }

    // epilogue: C-layout row = quad*4+r, col = lx
    int mrow0 = m0 + wm * 32 + quad * 4;
    if (wsel == 2) {
#pragma unroll
        for (int mf = 0; mf < 2; mf++) {
            int mbase = mrow0 + mf * 16;
            int batch = mbase >> 12;
            int t     = mbase & 4095;
#pragma unroll
            for (int nf = 0; nf < 4; nf++) {
                int n = wn * 64 + nf * 16 + lx;
                us4 pv;
#pragma unroll
                for (int r = 0; r < 4; r++) pv[r] = bfru(acc[mf][nf][r]);
                *(us4*)&vT[(size_t)batch * D_ * T_ + (size_t)n * T_ + t] = pv;
            }
        }
    } else {
        uint16_t* dst = (wsel == 0) ? qb : kb;
        float sc = (wsel == 0) ? QSCALE : 1.0f;
#pragma unroll
        for (int mf = 0; mf < 2; mf++)
#pragma unroll
            for (int nf = 0; nf < 4; nf++) {
                int n = wn * 64 + nf * 16 + lx;
#pragma unroll
                for (int r = 0; r < 4; r++)
                    dst[(size_t)(mrow0 + mf * 16 + r) * D_ + n] = bfru(acc[mf][nf][r] * sc);
            }
    }
}

// ---------------------------------------------------------------------------
// Kernel 3: split-K flash attention, 512-thread blocks (8 waves, 128 Q-rows)
// sharing K/V LDS -> 3 blocks/CU = 24 waves/CU. Chunks of <=8 key-tiles(64).
// grid = 4 batches x 144 chunks = 576 blocks, longest-first.
// ---------------------------------------------------------------------------
#define KST 136  // 128+8 (272B row stride, 16B aligned)
#define VST 72   // 64+8  (144B row stride, 16B aligned)

__global__ __launch_bounds__(512, 6) void attn(const uint16_t* __restrict__ qb,
                                               const uint16_t* __restrict__ kb,
                                               const uint16_t* __restrict__ vT,
                                               uint16_t* __restrict__ part,
                                               float* __restrict__ ml) {
    __shared__ __align__(16) uint16_t K_lds[64 * KST];   // 17408 B
    __shared__ __align__(16) uint16_t V_lds[128 * VST];  // 18432 B
    __shared__ __align__(16) uint16_t P_lds[8][16 * VST];// 18432 B  => 54272 total

    int tid  = threadIdx.x;
    int lane = tid & 63;
    int wave = tid >> 6;    // 0..7 -> q-rows wave*16..+15
    int quad = lane >> 4;
    int lx   = lane & 15;

    // decode blockIdx -> (batch, logical chunk L), longest chunks first
    int batch = blockIdx.x & 3;
    int L     = NCHUNK_PB - 1 - (blockIdx.x >> 2);
    int g = 0;
    while (g < 7 && 2 * (g + 1) * (g + 2) <= L) g++;
    int rem   = L - 2 * g * (g + 1);
    int jt2   = 4 * g + rem / (g + 1);
    int chunk = rem - (rem / (g + 1)) * (g + 1);
    int lidx  = batch * NCHUNK_PB + L;

    int q0     = jt2 * 128;
    int st0    = chunk * 8;
    int ntiles = min(8, 2 * jt2 + 2 - st0);
    int wrow0  = q0 + wave * 16;

    bf16x8 qf[4];
    {
        const uint16_t* qp = qb + (size_t)(batch * T_ + wrow0 + lx) * D_ + quad * 8;
#pragma unroll
        for (int kc = 0; kc < 4; kc++) qf[kc] = *(const bf16x8*)(qp + kc * 32);
    }

    f32x4 o[8];
    for (int i = 0; i < 8; i++) o[i] = (f32x4){0.f, 0.f, 0.f, 0.f};
    float m_i[4], l_i[4];
    for (int r = 0; r < 4; r++) { m_i[r] = -INFINITY; l_i[r] = 0.f; }

    int krow = tid >> 3, kcb = (tid & 7) * 16;  // K: 16 elems/thread
    int vd   = tid >> 2, vsb = (tid & 3) * 16;  // V: 16 elems/thread

    for (int it = 0; it < ntiles; it++) {
        int s0 = (st0 + it) * 64;
        // stage K tile [64 keys][128 d]
        {
            const uint16_t* kp = kb + (size_t)(batch * T_ + s0 + krow) * D_ + kcb;
            *(us8*)&K_lds[krow * KST + kcb]     = *(const us8*)kp;
            *(us8*)&K_lds[krow * KST + kcb + 8] = *(const us8*)(kp + 8);
        }
        // stage V^T tile [128 d][64 keys]
        {
            const uint16_t* vp = vT + (size_t)batch * D_ * T_ + (size_t)vd * T_ + s0 + vsb;
            *(us8*)&V_lds[vd * VST + vsb]     = *(const us8*)vp;
            *(us8*)&V_lds[vd * VST + vsb + 8] = *(const us8*)(vp + 8);
        }
        __syncthreads();

        // waves whose 16 rows are entirely above this key tile skip compute
        if (s0 <= wrow0 + 15) {
            // S = Q K^T (pre-scaled by QSCALE, log2 domain)
            f32x4 s[4];
            for (int nf = 0; nf < 4; nf++) s[nf] = (f32x4){0.f, 0.f, 0.f, 0.f};
#pragma unroll
            for (int kc = 0; kc < 4; kc++)
#pragma unroll
                for (int nf = 0; nf < 4; nf++) {
                    bf16x8 kf = *(const bf16x8*)&K_lds[(nf * 16 + lx) * KST + kc * 32 + quad * 8];
                    s[nf] = __builtin_amdgcn_mfma_f32_16x16x32_bf16(qf[kc], kf, s[nf], 0, 0, 0);
                }

            float p[4][4];
#pragma unroll
            for (int nf = 0; nf < 4; nf++)
#pragma unroll
                for (int r = 0; r < 4; r++) p[nf][r] = s[nf][r];

            // causal mask only where the tile straddles this wave's rows
            if (s0 + 63 > wrow0) {
                int rowg = wrow0 + quad * 4;
#pragma unroll
                for (int nf = 0; nf < 4; nf++) {
                    int colg = s0 + nf * 16 + lx;
#pragma unroll
                    for (int r = 0; r < 4; r++)
                        if (colg > rowg + r) p[nf][r] = -INFINITY;
                }
            }

            // row max across nf then 16 lanes
            float rm[4];
#pragma unroll
            for (int r = 0; r < 4; r++)
                rm[r] = fmaxf(fmaxf(p[0][r], p[1][r]), fmaxf(p[2][r], p[3][r]));
#pragma unroll
            for (int off = 1; off < 16; off <<= 1)
#pragma unroll
                for (int r = 0; r < 4; r++)
                    rm[r] = fmaxf(rm[r], __shfl_xor(rm[r], off, 64));

            float alpha[4], rs[4];
#pragma unroll
            for (int r = 0; r < 4; r++) {
                float mn = fmaxf(m_i[r], rm[r]);
                alpha[r] = exp2f(m_i[r] - mn);
                m_i[r]   = mn;
                float sum = 0.f;
#pragma unroll
                for (int nf = 0; nf < 4; nf++) {
                    float e = exp2f(p[nf][r] - mn);
                    p[nf][r] = e;
                    sum += e;
                }
                rs[r] = sum;
            }
#pragma unroll
            for (int off = 1; off < 16; off <<= 1)
#pragma unroll
                for (int r = 0; r < 4; r++)
                    rs[r] += __shfl_xor(rs[r], off, 64);
#pragma unroll
            for (int r = 0; r < 4; r++) l_i[r] = l_i[r] * alpha[r] + rs[r];
#pragma unroll
            for (int i = 0; i < 8; i++)
#pragma unroll
                for (int r = 0; r < 4; r++) o[i][r] *= alpha[r];

            // P (C-layout) -> LDS, pair-packed b32 writes from even lanes
#pragma unroll
            for (int nf = 0; nf < 4; nf++)
#pragma unroll
                for (int r = 0; r < 4; r++) {
                    uint32_t u  = __float_as_uint(p[nf][r]) + 0x8000u;
                    uint32_t pu = (uint32_t)__shfl_xor((int)u, 1, 64);
                    uint32_t pk = __builtin_amdgcn_perm(pu, u, 0x07060302);
                    if ((lane & 1) == 0)
                        *(uint32_t*)&P_lds[wave][(quad * 4 + r) * VST + nf * 16 + lx] = pk;
                }

            bf16x8 pf[2];
            pf[0] = *(const bf16x8*)&P_lds[wave][lx * VST + quad * 8];
            pf[1] = *(const bf16x8*)&P_lds[wave][lx * VST + 32 + quad * 8];
#pragma unroll
            for (int nf = 0; nf < 8; nf++)
#pragma unroll
                for (int kc = 0; kc < 2; kc++) {
                    bf16x8 vf = *(const bf16x8*)&V_lds[(nf * 16 + lx) * VST + kc * 32 + quad * 8];
                    o[nf] = __builtin_amdgcn_mfma_f32_16x16x32_bf16(pf[kc], vf, o[nf], 0, 0, 0);
                }
        }
        __syncthreads();
    }

    // write unnormalized partial (bf16) + (m, l) at the LOGICAL index
    uint16_t* pp = part + (size_t)lidx * (128 * 128);
#pragma unroll
    for (int nf = 0; nf < 8; nf++)
#pragma unroll
        for (int r = 0; r < 4; r++) {
            int lrow = wave * 16 + quad * 4 + r;
            pp[lrow * 128 + nf * 16 + lx] = bfru(o[nf][r]);
        }
    if (lx == 0) {
#pragma unroll
        for (int r = 0; r < 4; r++) {
            int lrow = wave * 16 + quad * 4 + r;
            ml[(size_t)lidx * 256 + lrow * 2]     = m_i[r];
            ml[(size_t)lidx * 256 + lrow * 2 + 1] = l_i[r];
        }
    }
}

// ---------------------------------------------------------------------------
// Kernel 4: combine split-K partials (bf16 partials, m in log2 domain).
// Block = (batch, 128-row q-tile); 512 threads.
// ---------------------------------------------------------------------------
__global__ __launch_bounds__(512) void combine(const uint16_t* __restrict__ part,
                                               const float* __restrict__ ml,
                                               float* __restrict__ out) {
    int bidx  = blockIdx.x;
    int batch = bidx >> 5;
    int jt2   = bidx & 31;
    int q     = jt2 >> 2, r = jt2 & 3;
    int base  = batch * NCHUNK_PB + 2 * q * (q + 1) + r * (q + 1);
    int nch   = q + 1;

    int tid  = threadIdx.x;
    int lrow = tid >> 2;
    int c0   = (tid & 3) * 32;

    float M = -INFINITY;
    for (int c = 0; c < nch; c++)
        M = fmaxf(M, ml[(size_t)(base + c) * 256 + lrow * 2]);

    float Lsum = 0.f;
    f32x4 acc[8];
#pragma unroll
    for (int i = 0; i < 8; i++) acc[i] = (f32x4){0.f, 0.f, 0.f, 0.f};

    for (int c = 0; c < nch; c++) {
        float m = ml[(size_t)(base + c) * 256 + lrow * 2];
        float l = ml[(size_t)(base + c) * 256 + lrow * 2 + 1];
        float w = exp2f(m - M);
        Lsum += l * w;
        const uint16_t* p = part + (size_t)(base + c) * (128 * 128) + lrow * 128 + c0;
#pragma unroll
        for (int i = 0; i < 4; i++) {
            us8 v = *(const us8*)(p + i * 8);
#pragma unroll
            for (int j = 0; j < 8; j++)
                acc[i * 2 + (j >> 2)][j & 3] += bf2f(v[j]) * w;
        }
    }
    float inv = 1.f / Lsum;
    size_t row = (size_t)(batch * T_ + jt2 * 128 + lrow);
#pragma unroll
    for (int i = 0; i < 8; i++)
        *(f32x4*)(out + row * 128 + c0 + i * 4) = acc[i] * inv;
}

// ---------------------------------------------------------------------------
extern "C" void kernel_launch(void* const* d_in, const int* in_sizes, int n_in,
                              void* d_out, int out_size, void* d_ws, size_t ws_size,
                              hipStream_t stream) {
    const float* x  = (const float*)d_in[0];
    const float* Wq = (const float*)d_in[1];
    const float* Wk = (const float*)d_in[2];
    const float* Wv = (const float*)d_in[3];
    float* out = (float*)d_out;

    uint16_t* ws = (uint16_t*)d_ws;
    uint16_t* qb = ws;                                   // 16384*128 bf16
    uint16_t* kb = qb + (size_t)16384 * 128;
    uint16_t* vT = kb + (size_t)16384 * 128;
    uint16_t* WT = vT + (size_t)16384 * 128;             // 3*128*1024
    uint16_t* part = WT + (size_t)3 * D_ * C_;           // 576*128*128 bf16
    float* ml = (float*)(part + (size_t)4 * NCHUNK_PB * 128 * 128);  // 576*256 fp32

    prep_w<<<dim3((3 * D_ * C_ + 255) / 256), dim3(256), 0, stream>>>(Wq, Wk, Wv, WT);
    qkv_gemm<<<dim3(3 * (16384 / 64)), dim3(256), 0, stream>>>(x, WT, qb, kb, vT);
    attn<<<dim3(B_ * NCHUNK_PB), dim3(512), 0, stream>>>(qb, kb, vT, part, ml);
    combine<<<dim3(B_ * (T_ / 128)), dim3(512), 0, stream>>>(part, ml, out);
}

// Round 7
// 202.219 us; speedup vs baseline: 1.2755x; 1.2755x over previous
//
#include <hip/hip_runtime.h>
#include <stdint.h>

typedef __bf16 bf16_t;
typedef bf16_t bf16x8 __attribute__((ext_vector_type(8)));
typedef float f32x4 __attribute__((ext_vector_type(4)));
typedef unsigned short us8 __attribute__((ext_vector_type(8)));
typedef unsigned short us4 __attribute__((ext_vector_type(4)));
typedef unsigned int u32x4 __attribute__((ext_vector_type(4)));

#define B_ 4
#define T_ 4096
#define C_ 1024
#define D_ 128

#define NCHUNK_PB 288   // per batch: sum over 64 q-tiles of ceil((jt+1)/8)
#define QSCALE 0.12751744f  // (1/sqrt(128)) * log2(e), folded into Q
#define M0 14.0f            // fixed softmax base (log2 domain); cancels in combine

__device__ __forceinline__ uint16_t f2bf(float f) {
    union { float f; uint32_t u; } v; v.f = f;
    uint32_t u = v.u;
    uint32_t r = (u + 0x7fffu + ((u >> 16) & 1u)) >> 16;
    return (uint16_t)r;
}

// round-half-up bf16 (2 VALU)
__device__ __forceinline__ uint16_t bfru(float f) {
    return (uint16_t)((__float_as_uint(f) + 0x8000u) >> 16);
}

__device__ __forceinline__ float bf2f(uint16_t u) {
    return __uint_as_float((uint32_t)u << 16);
}

// ---------------------------------------------------------------------------
// Kernel 1: W[C,D] fp32 -> WT[w][n][k] bf16 (transposed), w in {q,k,v}
// ---------------------------------------------------------------------------
__global__ __launch_bounds__(256) void prep_w(const float* __restrict__ Wq,
                                              const float* __restrict__ Wk,
                                              const float* __restrict__ Wv,
                                              uint16_t* __restrict__ WT) {
    int idx = blockIdx.x * 256 + threadIdx.x;
    if (idx >= 3 * D_ * C_) return;
    int w   = idx / (D_ * C_);
    int rem = idx - w * (D_ * C_);
    int n   = rem / C_;
    int k   = rem - n * C_;
    const float* W = (w == 0) ? Wq : (w == 1) ? Wk : Wv;
    WT[idx] = f2bf(W[(size_t)k * D_ + n]);
}

// ---------------------------------------------------------------------------
// Kernel 2: QKV projection (R4 structure). grid = 3 W x 256 M-tiles(64 rows).
// BK=64. Q gets QSCALE folded in.
// ---------------------------------------------------------------------------
#define GST 72   // 64+8 elems leading-dim pad

__global__ __launch_bounds__(256) void qkv_gemm(const float* __restrict__ x,
                                                const uint16_t* __restrict__ WT,
                                                uint16_t* __restrict__ qb,
                                                uint16_t* __restrict__ kb,
                                                uint16_t* __restrict__ vT) {
    __shared__ __align__(16) uint16_t A_lds[64 * GST];
    __shared__ __align__(16) uint16_t W_lds[128 * GST];

    int tid  = threadIdx.x;
    int lane = tid & 63;
    int wave = tid >> 6;
    int quad = lane >> 4;
    int lx   = lane & 15;
    int wm   = wave >> 1, wn = wave & 1;

    int bx   = blockIdx.x;
    int wsel = bx % 3;
    int m0   = (bx / 3) * 64;
    const uint16_t* Wp = WT + (size_t)wsel * (D_ * C_);

    f32x4 acc[2][4];
    for (int mf = 0; mf < 2; mf++)
        for (int nf = 0; nf < 4; nf++)
            acc[mf][nf] = (f32x4){0.f, 0.f, 0.f, 0.f};

    int arow = tid >> 2, acb = (tid & 3) * 16;  // A: 16 floats/thread
    int wrow = tid >> 1, wcb = (tid & 1) * 32;  // W: 32 bf16/thread

    for (int k0 = 0; k0 < C_; k0 += 64) {
        // stage A (fp32 -> bf16 packed via v_perm)
        {
            const float* xp = x + (size_t)(m0 + arow) * C_ + k0 + acb;
            uint32_t d[8];
#pragma unroll
            for (int j = 0; j < 4; j++) {
                float4 f = *(const float4*)(xp + j * 4);
                uint32_t u0 = __float_as_uint(f.x) + 0x8000u;
                uint32_t u1 = __float_as_uint(f.y) + 0x8000u;
                uint32_t u2 = __float_as_uint(f.z) + 0x8000u;
                uint32_t u3 = __float_as_uint(f.w) + 0x8000u;
                d[2 * j]     = __builtin_amdgcn_perm(u1, u0, 0x07060302);
                d[2 * j + 1] = __builtin_amdgcn_perm(u3, u2, 0x07060302);
            }
            *(u32x4*)&A_lds[arow * GST + acb]     = (u32x4){d[0], d[1], d[2], d[3]};
            *(u32x4*)&A_lds[arow * GST + acb + 8] = (u32x4){d[4], d[5], d[6], d[7]};
        }
        // stage W slice (bf16, transposed already)
        {
            const uint16_t* wp = Wp + (size_t)wrow * C_ + k0 + wcb;
#pragma unroll
            for (int i = 0; i < 4; i++)
                *(us8*)&W_lds[wrow * GST + wcb + i * 8] = *(const us8*)(wp + i * 8);
        }
        __syncthreads();

#pragma unroll
        for (int kc = 0; kc < 2; kc++) {
            bf16x8 af[2];
#pragma unroll
            for (int mf = 0; mf < 2; mf++)
                af[mf] = *(const bf16x8*)&A_lds[(wm * 32 + mf * 16 + lx) * GST + kc * 32 + quad * 8];
#pragma unroll
            for (int nf = 0; nf < 4; nf++) {
                bf16x8 bf = *(const bf16x8*)&W_lds[(wn * 64 + nf * 16 + lx) * GST + kc * 32 + quad * 8];
                acc[0][nf] = __builtin_amdgcn_mfma_f32_16x16x32_bf16(af[0], bf, acc[0][nf], 0, 0, 0);
                acc[1][nf] = __builtin_amdgcn_mfma_f32_16x16x32_bf16(af[1], bf, acc[1][nf], 0, 0, 0);
            }
        }
        __syncthreads();
    }

    // epilogue: C-layout row = quad*4+r, col = lx
    int mrow0 = m0 + wm * 32 + quad * 4;
    if (wsel == 2) {
#pragma unroll
        for (int mf = 0; mf < 2; mf++) {
            int mbase = mrow0 + mf * 16;
            int batch = mbase >> 12;
            int t     = mbase & 4095;
#pragma unroll
            for (int nf = 0; nf < 4; nf++) {
                int n = wn * 64 + nf * 16 + lx;
                us4 pv;
#pragma unroll
                for (int r = 0; r < 4; r++) pv[r] = bfru(acc[mf][nf][r]);
                *(us4*)&vT[(size_t)batch * D_ * T_ + (size_t)n * T_ + t] = pv;
            }
        }
    } else {
        uint16_t* dst = (wsel == 0) ? qb : kb;
        float sc = (wsel == 0) ? QSCALE : 1.0f;
#pragma unroll
        for (int mf = 0; mf < 2; mf++)
#pragma unroll
            for (int nf = 0; nf < 4; nf++) {
                int n = wn * 64 + nf * 16 + lx;
#pragma unroll
                for (int r = 0; r < 4; r++)
                    dst[(size_t)(mrow0 + mf * 16 + r) * D_ + n] = bfru(acc[mf][nf][r] * sc);
            }
    }
}

// ---------------------------------------------------------------------------
// Kernel 3: split-K flash attention, fixed-base softmax (no online max),
// XOR-swizzled unpadded LDS: 40960 B -> 4 blocks/CU (16 waves/CU).
// Block = 256 threads, 64 Q-rows, chunk of <=8 key-tiles(64). Longest-first.
// Swizzle: 16B chunk index ^= (row & 7); bank-balanced for all patterns.
// ---------------------------------------------------------------------------
__global__ __launch_bounds__(256, 4) void attn(const uint16_t* __restrict__ qb,
                                               const uint16_t* __restrict__ kb,
                                               const uint16_t* __restrict__ vT,
                                               uint16_t* __restrict__ part,
                                               float* __restrict__ ml) {
    __shared__ __align__(16) uint16_t K_lds[64 * 128];    // 16384 B
    __shared__ __align__(16) uint16_t V_lds[128 * 64];    // 16384 B
    __shared__ __align__(16) uint16_t P_lds[4 * 16 * 64]; //  8192 B

    int tid  = threadIdx.x;
    int lane = tid & 63;
    int wave = tid >> 6;
    int quad = lane >> 4;
    int lx   = lane & 15;
    int lx7  = lx & 7;

    // decode blockIdx -> (batch, logical chunk L), longest chunks first
    int batch = blockIdx.x & 3;
    int L     = NCHUNK_PB - 1 - (blockIdx.x >> 2);
    int g = 0;
    while (g < 7 && 4 * (g + 1) * (g + 2) <= L) g++;
    int rem   = L - 4 * g * (g + 1);
    int jt    = 8 * g + rem / (g + 1);
    int chunk = rem - (rem / (g + 1)) * (g + 1);
    int lidx  = batch * NCHUNK_PB + L;

    int q0     = jt * 64;
    int st0    = chunk * 8;
    int ntiles = min(8, jt - st0 + 1);

    bf16x8 qf[4];
    {
        const uint16_t* qp = qb + (size_t)(batch * T_ + q0 + wave * 16 + lx) * D_ + quad * 8;
#pragma unroll
        for (int kc = 0; kc < 4; kc++) qf[kc] = *(const bf16x8*)(qp + kc * 32);
    }

    f32x4 o[8];
    for (int i = 0; i < 8; i++) o[i] = (f32x4){0.f, 0.f, 0.f, 0.f};
    float l_i[4] = {0.f, 0.f, 0.f, 0.f};

    int krow = tid >> 2, kc0 = (tid & 3) * 4;  // K: 4 chunks(16B) per thread
    int vd   = tid >> 1, vc0 = (tid & 1) * 4;  // V: 4 chunks per thread

    for (int it = 0; it < ntiles; it++) {
        int s0 = (st0 + it) * 64;
        // stage K tile [64 keys][128 d], chunk-swizzled
        {
            const uint16_t* kp = kb + (size_t)(batch * T_ + s0 + krow) * D_ + kc0 * 8;
#pragma unroll
            for (int i = 0; i < 4; i++)
                *(us8*)&K_lds[krow * 128 + (((kc0 + i) ^ (krow & 7)) * 8)] = *(const us8*)(kp + i * 8);
        }
        // stage V^T tile [128 d][64 keys], chunk-swizzled
        {
            const uint16_t* vp = vT + (size_t)batch * D_ * T_ + (size_t)vd * T_ + s0 + vc0 * 8;
#pragma unroll
            for (int i = 0; i < 4; i++)
                *(us8*)&V_lds[vd * 64 + (((vc0 + i) ^ (vd & 7)) * 8)] = *(const us8*)(vp + i * 8);
        }
        __syncthreads();

        // S = Q K^T (pre-scaled by QSCALE, log2 domain)
        f32x4 s[4];
        for (int nf = 0; nf < 4; nf++) s[nf] = (f32x4){0.f, 0.f, 0.f, 0.f};
#pragma unroll
        for (int kc = 0; kc < 4; kc++)
#pragma unroll
            for (int nf = 0; nf < 4; nf++) {
                bf16x8 kf = *(const bf16x8*)&K_lds[(nf * 16 + lx) * 128 + (((kc * 4 + quad) ^ lx7) * 8)];
                s[nf] = __builtin_amdgcn_mfma_f32_16x16x32_bf16(qf[kc], kf, s[nf], 0, 0, 0);
            }

        float p[4][4];
#pragma unroll
        for (int nf = 0; nf < 4; nf++)
#pragma unroll
            for (int r = 0; r < 4; r++) p[nf][r] = s[nf][r];

        // causal mask only on the diagonal tile (wave-uniform branch)
        if (st0 + it == jt) {
            int rowg = q0 + wave * 16 + quad * 4;
#pragma unroll
            for (int nf = 0; nf < 4; nf++) {
                int colg = s0 + nf * 16 + lx;
#pragma unroll
                for (int r = 0; r < 4; r++)
                    if (colg > rowg + r) p[nf][r] = -INFINITY;
            }
        }

        // p = exp2(s - M0); accumulate denominator per-lane (no reductions)
#pragma unroll
        for (int nf = 0; nf < 4; nf++)
#pragma unroll
            for (int r = 0; r < 4; r++)
                p[nf][r] = exp2f(p[nf][r] - M0);
#pragma unroll
        for (int r = 0; r < 4; r++)
            l_i[r] += (p[0][r] + p[1][r]) + (p[2][r] + p[3][r]);

        // P (C-layout) -> LDS, pair-packed b32 writes from even lanes, swizzled
#pragma unroll
        for (int nf = 0; nf < 4; nf++)
#pragma unroll
            for (int r = 0; r < 4; r++) {
                uint32_t u  = __float_as_uint(p[nf][r]) + 0x8000u;
                uint32_t pu = (uint32_t)__shfl_xor((int)u, 1, 64);
                uint32_t pk = __builtin_amdgcn_perm(pu, u, 0x07060302);
                if ((lane & 1) == 0) {
                    int prow = quad * 4 + r;
                    int pchk = nf * 2 + (lx >> 3);
                    *(uint32_t*)&P_lds[wave * 1024 + prow * 64 + ((pchk ^ (prow & 7)) * 8) + lx7] = pk;
                }
            }

        bf16x8 pf[2];
        pf[0] = *(const bf16x8*)&P_lds[wave * 1024 + lx * 64 + ((quad ^ lx7) * 8)];
        pf[1] = *(const bf16x8*)&P_lds[wave * 1024 + lx * 64 + (((4 + quad) ^ lx7) * 8)];
#pragma unroll
        for (int nf = 0; nf < 8; nf++)
#pragma unroll
            for (int kc = 0; kc < 2; kc++) {
                bf16x8 vf = *(const bf16x8*)&V_lds[(nf * 16 + lx) * 64 + (((kc * 4 + quad) ^ lx7) * 8)];
                o[nf] = __builtin_amdgcn_mfma_f32_16x16x32_bf16(pf[kc], vf, o[nf], 0, 0, 0);
            }
        __syncthreads();
    }

    // reduce l across the 16 lanes of each quarter-row group (once per kernel)
#pragma unroll
    for (int off = 1; off < 16; off <<= 1)
#pragma unroll
        for (int r = 0; r < 4; r++)
            l_i[r] += __shfl_xor(l_i[r], off, 64);

    // write unnormalized partial (bf16) + l at the LOGICAL index
    uint16_t* pp = part + (size_t)lidx * (64 * 128);
#pragma unroll
    for (int nf = 0; nf < 8; nf++)
#pragma unroll
        for (int r = 0; r < 4; r++) {
            int lrow = wave * 16 + quad * 4 + r;
            pp[lrow * 128 + nf * 16 + lx] = bfru(o[nf][r]);
        }
    if (lx == 0) {
#pragma unroll
        for (int r = 0; r < 4; r++)
            ml[(size_t)lidx * 64 + wave * 16 + quad * 4 + r] = l_i[r];
    }
}

// ---------------------------------------------------------------------------
// Kernel 4: combine split-K partials: plain sums (fixed M0 cancels).
// Block = (batch, jt); 256 threads.
// ---------------------------------------------------------------------------
__global__ __launch_bounds__(256) void combine(const uint16_t* __restrict__ part,
                                               const float* __restrict__ ml,
                                               float* __restrict__ out) {
    int bidx  = blockIdx.x;
    int batch = bidx >> 6;
    int jt    = bidx & 63;
    int g     = jt >> 3;
    int base  = batch * NCHUNK_PB + jt + g * (jt - 4 * g - 4);
    int nch   = g + 1;

    int tid  = threadIdx.x;
    int lrow = tid >> 2;
    int c0   = (tid & 3) * 32;

    float Lsum = 0.f;
    f32x4 acc[8];
#pragma unroll
    for (int i = 0; i < 8; i++) acc[i] = (f32x4){0.f, 0.f, 0.f, 0.f};

    for (int c = 0; c < nch; c++) {
        Lsum += ml[(size_t)(base + c) * 64 + lrow];
        const uint16_t* p = part + (size_t)(base + c) * (64 * 128) + lrow * 128 + c0;
#pragma unroll
        for (int i = 0; i < 4; i++) {
            us8 v = *(const us8*)(p + i * 8);
#pragma unroll
            for (int j = 0; j < 8; j++)
                acc[i * 2 + (j >> 2)][j & 3] += bf2f(v[j]);
        }
    }
    float inv = 1.f / Lsum;
    size_t row = (size_t)(batch * T_ + jt * 64 + lrow);
#pragma unroll
    for (int i = 0; i < 8; i++)
        *(f32x4*)(out + row * 128 + c0 + i * 4) = acc[i] * inv;
}

// ---------------------------------------------------------------------------
extern "C" void kernel_launch(void* const* d_in, const int* in_sizes, int n_in,
                              void* d_out, int out_size, void* d_ws, size_t ws_size,
                              hipStream_t stream) {
    const float* x  = (const float*)d_in[0];
    const float* Wq = (const float*)d_in[1];
    const float* Wk = (const float*)d_in[2];
    const float* Wv = (const float*)d_in[3];
    float* out = (float*)d_out;

    uint16_t* ws = (uint16_t*)d_ws;
    uint16_t* qb = ws;                                   // 16384*128 bf16
    uint16_t* kb = qb + (size_t)16384 * 128;
    uint16_t* vT = kb + (size_t)16384 * 128;
    uint16_t* WT = vT + (size_t)16384 * 128;             // 3*128*1024
    uint16_t* part = WT + (size_t)3 * D_ * C_;           // 1152*64*128 bf16
    float* ml = (float*)(part + (size_t)4 * NCHUNK_PB * 64 * 128);  // 1152*64 fp32

    prep_w<<<dim3((3 * D_ * C_ + 255) / 256), dim3(256), 0, stream>>>(Wq, Wk, Wv, WT);
    qkv_gemm<<<dim3(3 * (16384 / 64)), dim3(256), 0, stream>>>(x, WT, qb, kb, vT);
    attn<<<dim3(B_ * NCHUNK_PB), dim3(256), 0, stream>>>(qb, kb, vT, part, ml);
    combine<<<dim3(B_ * (T_ / 64)), dim3(256), 0, stream>>>(part, ml, out);
}